// Round 5
// baseline (310.543 us; speedup 1.0000x reference)
//
#include <hip/hip_runtime.h>
#include <hip/hip_cooperative_groups.h>
#include <hip/hip_bf16.h>
#include <math.h>

namespace cg = cooperative_groups;

typedef __attribute__((ext_vector_type(8))) short bf16x8_t;
typedef __attribute__((ext_vector_type(4))) int i32x4_t;
typedef __attribute__((ext_vector_type(2))) int i32x2_t;
typedef __attribute__((ext_vector_type(4))) float f32x4_t;
typedef __attribute__((ext_vector_type(16))) float f32x16_t;

#define NH 4
#define HD 16
#define NN 4096
#define CC 64
#define JC 1024  // keys per segment (SK=4)

__device__ __forceinline__ short f2bf(float f) {
  union { float f; unsigned u; } v; v.f = f;
  unsigned r = v.u + 0x7FFFu + ((v.u >> 16) & 1u);
  return (short)(r >> 16);
}

// ================= fused cooperative kernel =================
// grid 1024 x 256 (4 blocks/CU co-resident). 3 phases with grid.sync between.
__global__ __launch_bounds__(256, 4) void fused_kernel(
    const float* __restrict__ x, const float* __restrict__ tpm,
    const float* __restrict__ qkv_w, const float* __restrict__ qkv_b,
    const float* __restrict__ temperature,
    const float* __restrict__ proj_w, const float* __restrict__ proj_b,
    float* __restrict__ out,
    short* __restrict__ Q, short* __restrict__ K, short* __restrict__ Kp,
    short* __restrict__ V, float* __restrict__ ts, short* __restrict__ ones,
    float* __restrict__ OP, float* __restrict__ LP) {
  __shared__ float smem[64 * 64];  // 16 KB: xs in phase 1, pv in phase 3
  cg::grid_group grid = cg::this_grid();
  int bid = blockIdx.x;
  int t = threadIdx.x;

  // ---------------- phase 1: QKV + ts + Kp + ones (blocks 0..383) ----------------
  if (bid < 17) {
    int idx = bid * 256 + t;
    if (idx < 4352) ones[idx] = (short)0x3F80;
  }
  if (bid < 384) {
    float (*xs)[64] = (float (*)[64])smem;
    int nt = bid % 64;
    int which = (bid / 64) % 3;
    int b = bid / 192;
    int nl = t & 63;
    int h = __builtin_amdgcn_readfirstlane(t >> 6);  // wave-uniform head
    int n0 = nt * 64;
    int n = n0 + nl;

    {
      int c0 = t >> 6;
      const float* xb = x + ((size_t)b * 64) * NN + n0;
#pragma unroll
      for (int k = 0; k < 16; ++k) {
        int c = c0 + 4 * k;
        xs[c][nl] = xb[(size_t)c * NN + nl];
      }
    }
    __syncthreads();

    int obase = which * 64 + h * 16;
    float acc[16];
#pragma unroll
    for (int d = 0; d < 16; ++d) acc[d] = qkv_b[obase + d];

#pragma unroll 1
    for (int cb = 0; cb < 64; cb += 8) {
      float xr[8];
#pragma unroll
      for (int cc = 0; cc < 8; ++cc) xr[cc] = xs[cb + cc][nl];
#pragma unroll
      for (int d = 0; d < 16; ++d) {
#pragma unroll
        for (int cc = 0; cc < 8; ++cc)
          acc[d] += qkv_w[(obase + d) * 64 + cb + cc] * xr[cc];
      }
    }

    if (which == 2) {
#pragma unroll
      for (int d = 0; d < 16; ++d)
        V[(((size_t)b * NH + h) * HD + d) * NN + n] = f2bf(acc[d]);
      if (h == 0) {
        float tc = temperature[0];
        tc = fminf(fmaxf(tc, 0.1f), 2.0f);
        float tp = tpm[(size_t)b * NN + n];
        tp = fminf(fmaxf(tp, 0.01f), 1.0f);
        ts[(size_t)b * NN + n] = 0.125f * tc * tp * 1.44269504088896341f;
      }
    } else if (which == 0) {
      short pk[16];
#pragma unroll
      for (int d = 0; d < 16; ++d) pk[d] = f2bf(acc[d]);
      short* dst = Q + (((size_t)b * NH + h) * NN + n) * HD;
      *(bf16x8_t*)dst = *(bf16x8_t*)&pk[0];
      *(bf16x8_t*)(dst + 8) = *(bf16x8_t*)&pk[8];
    } else {
      float tc = temperature[0];
      tc = fminf(fmaxf(tc, 0.1f), 2.0f);
      float tp = tpm[(size_t)b * NN + n];
      tp = fminf(fmaxf(tp, 0.01f), 1.0f);
      float tsn = 0.125f * tc * tp * 1.44269504088896341f;
      short pk[16], pkp[16];
#pragma unroll
      for (int d = 0; d < 16; ++d) { pk[d] = f2bf(acc[d]); pkp[d] = f2bf(acc[d] * tsn); }
      short* dst = K + (((size_t)b * NH + h) * NN + n) * HD;
      *(bf16x8_t*)dst = *(bf16x8_t*)&pk[0];
      *(bf16x8_t*)(dst + 8) = *(bf16x8_t*)&pk[8];
      short* dstp = Kp + (((size_t)b * NH + h) * NN + n) * HD;
      *(bf16x8_t*)dstp = *(bf16x8_t*)&pkp[0];
      *(bf16x8_t*)(dstp + 8) = *(bf16x8_t*)&pkp[8];
    }
  }

  grid.sync();

  // ---------------- phase 2: attention (all 1024 blocks; SK=4) ----------------
  {
    int tile = bid & 31;
    int bh = (bid >> 5) & 7;
    int seg = bid >> 8;
    int b = bh >> 2, h = bh & 3;

    int w = t >> 6;
    int lane = t & 63;
    int half = lane >> 5;
    int l31 = lane & 31;

    int qi0 = tile * 128 + w * 32;
    const short* Qb = Q + (((size_t)b * NH + h) * NN) * HD;
    const short* Kb = K + (((size_t)b * NH + h) * NN) * HD;
    const short* Kpb = Kp + (((size_t)b * NH + h) * NN) * HD;
    const short* Vb = V + (((size_t)b * NH + h) * HD) * NN;

    float tsi = ts[(size_t)b * NN + qi0 + l31];
    bf16x8_t qf = *(const bf16x8_t*)(Qb + (size_t)(qi0 + l31) * HD + 8 * half);

    int jbase = seg * JC;
    const short* vrow = (l31 < 16) ? (Vb + (size_t)l31 * NN + jbase) : ones;

    f32x16_t acc = {0.f,0.f,0.f,0.f,0.f,0.f,0.f,0.f,0.f,0.f,0.f,0.f,0.f,0.f,0.f,0.f};
    const f32x16_t z16 = {0.f,0.f,0.f,0.f,0.f,0.f,0.f,0.f,0.f,0.f,0.f,0.f,0.f,0.f,0.f,0.f};

#pragma unroll 2
    for (int jj = 0; jj < JC; jj += 32) {
      const short* kptr = Kb + (size_t)(jbase + jj + l31) * HD + 8 * half;
      const short* kpptr = Kpb + (size_t)(jbase + jj + l31) * HD + 8 * half;
      bf16x8_t ak = *(const bf16x8_t*)kptr;
      bf16x8_t akp = *(const bf16x8_t*)kpptr;
      f32x16_t s = __builtin_amdgcn_mfma_f32_32x32x16_bf16(ak, qf, z16, 0, 0, 0);
      f32x16_t sp = __builtin_amdgcn_mfma_f32_32x32x16_bf16(akp, qf, z16, 0, 0, 0);

      float p[16];
#pragma unroll
      for (int r = 0; r < 16; ++r)
        p[r] = __builtin_amdgcn_exp2f(s[r] * tsi + sp[r]);

      int wr[8];
#pragma unroll
      for (int m = 0; m < 8; ++m)
        asm("v_cvt_pk_bf16_f32 %0, %1, %2" : "=v"(wr[m]) : "v"(p[2 * m]), "v"(p[2 * m + 1]));

      i32x2_t s02 = __builtin_amdgcn_permlane32_swap(wr[0], wr[2], false, false);
      i32x2_t s13 = __builtin_amdgcn_permlane32_swap(wr[1], wr[3], false, false);
      i32x2_t s46 = __builtin_amdgcn_permlane32_swap(wr[4], wr[6], false, false);
      i32x2_t s57 = __builtin_amdgcn_permlane32_swap(wr[5], wr[7], false, false);
      union { i32x4_t i; bf16x8_t b; } pa0, pa1;
      pa0.i = (i32x4_t){s02[0], s13[0], s02[1], s13[1]};
      pa1.i = (i32x4_t){s46[0], s57[0], s46[1], s57[1]};

      bf16x8_t bv0 = *(const bf16x8_t*)(vrow + jj + 8 * half);
      bf16x8_t bv1 = *(const bf16x8_t*)(vrow + jj + 16 + 8 * half);
      acc = __builtin_amdgcn_mfma_f32_32x32x16_bf16(pa0.b, bv0, acc, 0, 0, 0);
      acc = __builtin_amdgcn_mfma_f32_32x32x16_bf16(pa1.b, bv1, acc, 0, 0, 0);
    }

    float* OPb = OP + ((((size_t)seg * 2 + b) * NH + h) * HD) * NN;
    float* LPb = LP + (((size_t)seg * 2 + b) * NH + h) * NN;
    if (l31 < 16) {
#pragma unroll
      for (int g4 = 0; g4 < 4; ++g4) {
        f32x4_t vv = {acc[4 * g4 + 0], acc[4 * g4 + 1], acc[4 * g4 + 2], acc[4 * g4 + 3]};
        *(f32x4_t*)(OPb + (size_t)l31 * NN + qi0 + 4 * half + 8 * g4) = vv;
      }
    } else if (l31 == 16) {
#pragma unroll
      for (int g4 = 0; g4 < 4; ++g4) {
        f32x4_t vv = {acc[4 * g4 + 0], acc[4 * g4 + 1], acc[4 * g4 + 2], acc[4 * g4 + 3]};
        *(f32x4_t*)(LPb + qi0 + 4 * half + 8 * g4) = vv;
      }
    }
  }

  grid.sync();

  // ---------------- phase 3: merge + proj (blocks 0..255) ----------------
  if (bid < 256) {
    float (*pv)[32] = (float (*)[32])smem;
    int b = bid >> 7;
    int n0 = (bid & 127) << 5;
    int nl = t & 31;
    int g = t >> 5;
    int n = n0 + nl;

    {
      int h = g >> 1;
      float ls = 0.f;
#pragma unroll
      for (int s = 0; s < 4; ++s)
        ls += LP[(((size_t)s * 2 + b) * NH + h) * NN + n];
      float inv = 1.0f / ls;
#pragma unroll
      for (int cc = 0; cc < 8; ++cc) {
        int c = g * 8 + cc;
        int d = c & 15;
        float a = 0.f;
#pragma unroll
        for (int s = 0; s < 4; ++s)
          a += OP[((((size_t)s * 2 + b) * NH + h) * HD + d) * NN + n];
        pv[c][nl] = a * inv;
      }
    }
    __syncthreads();
#pragma unroll
    for (int oo = 0; oo < 8; ++oo) {
      int o = g * 8 + oo;
      float a = proj_b[o];
#pragma unroll
      for (int c = 0; c < 64; ++c) a += proj_w[o * 64 + c] * pv[c][nl];
      out[((size_t)b * CC + o) * NN + n] = a;
    }
  }
}

// ================= fallback 3-kernel path (proven correct, R4) =================
__global__ __launch_bounds__(256) void qkv_kernel(
    const float* __restrict__ x, const float* __restrict__ tpm,
    const float* __restrict__ qkv_w, const float* __restrict__ qkv_b,
    const float* __restrict__ temperature,
    short* __restrict__ Q, short* __restrict__ K, short* __restrict__ Kp,
    short* __restrict__ V, float* __restrict__ ts, short* __restrict__ ones) {
  __shared__ float xs[64][64];
  int bid = blockIdx.x;
  if (bid < 17) {
    int idx = bid * 256 + threadIdx.x;
    if (idx < 4352) ones[idx] = (short)0x3F80;
  }
  int nt = bid % 64;
  int which = (bid / 64) % 3;
  int b = bid / 192;
  int t = threadIdx.x;
  int nl = t & 63;
  int h = __builtin_amdgcn_readfirstlane(t >> 6);
  int n0 = nt * 64;
  int n = n0 + nl;
  {
    int c0 = t >> 6;
    const float* xb = x + ((size_t)b * 64) * NN + n0;
#pragma unroll
    for (int k = 0; k < 16; ++k) {
      int c = c0 + 4 * k;
      xs[c][nl] = xb[(size_t)c * NN + nl];
    }
  }
  __syncthreads();
  int obase = which * 64 + h * 16;
  float acc[16];
#pragma unroll
  for (int d = 0; d < 16; ++d) acc[d] = qkv_b[obase + d];
#pragma unroll 1
  for (int cb = 0; cb < 64; cb += 8) {
    float xr[8];
#pragma unroll
    for (int cc = 0; cc < 8; ++cc) xr[cc] = xs[cb + cc][nl];
#pragma unroll
    for (int d = 0; d < 16; ++d) {
#pragma unroll
      for (int cc = 0; cc < 8; ++cc)
        acc[d] += qkv_w[(obase + d) * 64 + cb + cc] * xr[cc];
    }
  }
  if (which == 2) {
#pragma unroll
    for (int d = 0; d < 16; ++d)
      V[(((size_t)b * NH + h) * HD + d) * NN + n] = f2bf(acc[d]);
    if (h == 0) {
      float tc = temperature[0];
      tc = fminf(fmaxf(tc, 0.1f), 2.0f);
      float tp = tpm[(size_t)b * NN + n];
      tp = fminf(fmaxf(tp, 0.01f), 1.0f);
      ts[(size_t)b * NN + n] = 0.125f * tc * tp * 1.44269504088896341f;
    }
  } else if (which == 0) {
    short pk[16];
#pragma unroll
    for (int d = 0; d < 16; ++d) pk[d] = f2bf(acc[d]);
    short* dst = Q + (((size_t)b * NH + h) * NN + n) * HD;
    *(bf16x8_t*)dst = *(bf16x8_t*)&pk[0];
    *(bf16x8_t*)(dst + 8) = *(bf16x8_t*)&pk[8];
  } else {
    float tc = temperature[0];
    tc = fminf(fmaxf(tc, 0.1f), 2.0f);
    float tp = tpm[(size_t)b * NN + n];
    tp = fminf(fmaxf(tp, 0.01f), 1.0f);
    float tsn = 0.125f * tc * tp * 1.44269504088896341f;
    short pk[16], pkp[16];
#pragma unroll
    for (int d = 0; d < 16; ++d) { pk[d] = f2bf(acc[d]); pkp[d] = f2bf(acc[d] * tsn); }
    short* dst = K + (((size_t)b * NH + h) * NN + n) * HD;
    *(bf16x8_t*)dst = *(bf16x8_t*)&pk[0];
    *(bf16x8_t*)(dst + 8) = *(bf16x8_t*)&pk[8];
    short* dstp = Kp + (((size_t)b * NH + h) * NN + n) * HD;
    *(bf16x8_t*)dstp = *(bf16x8_t*)&pkp[0];
    *(bf16x8_t*)(dstp + 8) = *(bf16x8_t*)&pkp[8];
  }
}

__global__ __launch_bounds__(256, 4) void attn_kernel(
    const short* __restrict__ Q, const short* __restrict__ K, const short* __restrict__ Kp,
    const short* __restrict__ V, const short* __restrict__ ones, const float* __restrict__ ts,
    float* __restrict__ OP, float* __restrict__ LP, int jcount) {
  int bid = blockIdx.x;
  int tile = bid & 31;
  int bh = (bid >> 5) & 7;
  int seg = bid >> 8;
  int b = bh >> 2, h = bh & 3;
  int tid = threadIdx.x;
  int w = tid >> 6;
  int lane = tid & 63;
  int half = lane >> 5;
  int l31 = lane & 31;
  int qi0 = tile * 128 + w * 32;
  const short* Qb = Q + (((size_t)b * NH + h) * NN) * HD;
  const short* Kb = K + (((size_t)b * NH + h) * NN) * HD;
  const short* Kpb = Kp + (((size_t)b * NH + h) * NN) * HD;
  const short* Vb = V + (((size_t)b * NH + h) * HD) * NN;
  float tsi = ts[(size_t)b * NN + qi0 + l31];
  bf16x8_t qf = *(const bf16x8_t*)(Qb + (size_t)(qi0 + l31) * HD + 8 * half);
  int jbase = seg * jcount;
  const short* vrow = (l31 < 16) ? (Vb + (size_t)l31 * NN + jbase) : ones;
  f32x16_t acc = {0.f,0.f,0.f,0.f,0.f,0.f,0.f,0.f,0.f,0.f,0.f,0.f,0.f,0.f,0.f,0.f};
  const f32x16_t z16 = {0.f,0.f,0.f,0.f,0.f,0.f,0.f,0.f,0.f,0.f,0.f,0.f,0.f,0.f,0.f,0.f};
#pragma unroll 2
  for (int jj = 0; jj < jcount; jj += 32) {
    bf16x8_t ak = *(const bf16x8_t*)(Kb + (size_t)(jbase + jj + l31) * HD + 8 * half);
    bf16x8_t akp = *(const bf16x8_t*)(Kpb + (size_t)(jbase + jj + l31) * HD + 8 * half);
    f32x16_t s = __builtin_amdgcn_mfma_f32_32x32x16_bf16(ak, qf, z16, 0, 0, 0);
    f32x16_t sp = __builtin_amdgcn_mfma_f32_32x32x16_bf16(akp, qf, z16, 0, 0, 0);
    float p[16];
#pragma unroll
    for (int r = 0; r < 16; ++r)
      p[r] = __builtin_amdgcn_exp2f(s[r] * tsi + sp[r]);
    int wr[8];
#pragma unroll
    for (int m = 0; m < 8; ++m)
      asm("v_cvt_pk_bf16_f32 %0, %1, %2" : "=v"(wr[m]) : "v"(p[2 * m]), "v"(p[2 * m + 1]));
    i32x2_t s02 = __builtin_amdgcn_permlane32_swap(wr[0], wr[2], false, false);
    i32x2_t s13 = __builtin_amdgcn_permlane32_swap(wr[1], wr[3], false, false);
    i32x2_t s46 = __builtin_amdgcn_permlane32_swap(wr[4], wr[6], false, false);
    i32x2_t s57 = __builtin_amdgcn_permlane32_swap(wr[5], wr[7], false, false);
    union { i32x4_t i; bf16x8_t b; } pa0, pa1;
    pa0.i = (i32x4_t){s02[0], s13[0], s02[1], s13[1]};
    pa1.i = (i32x4_t){s46[0], s57[0], s46[1], s57[1]};
    bf16x8_t bv0 = *(const bf16x8_t*)(vrow + jj + 8 * half);
    bf16x8_t bv1 = *(const bf16x8_t*)(vrow + jj + 16 + 8 * half);
    acc = __builtin_amdgcn_mfma_f32_32x32x16_bf16(pa0.b, bv0, acc, 0, 0, 0);
    acc = __builtin_amdgcn_mfma_f32_32x32x16_bf16(pa1.b, bv1, acc, 0, 0, 0);
  }
  float* OPb = OP + ((((size_t)seg * 2 + b) * NH + h) * HD) * NN;
  float* LPb = LP + (((size_t)seg * 2 + b) * NH + h) * NN;
  if (l31 < 16) {
#pragma unroll
    for (int g4 = 0; g4 < 4; ++g4) {
      f32x4_t vv = {acc[4 * g4 + 0], acc[4 * g4 + 1], acc[4 * g4 + 2], acc[4 * g4 + 3]};
      *(f32x4_t*)(OPb + (size_t)l31 * NN + qi0 + 4 * half + 8 * g4) = vv;
    }
  } else if (l31 == 16) {
#pragma unroll
    for (int g4 = 0; g4 < 4; ++g4) {
      f32x4_t vv = {acc[4 * g4 + 0], acc[4 * g4 + 1], acc[4 * g4 + 2], acc[4 * g4 + 3]};
      *(f32x4_t*)(LPb + qi0 + 4 * half + 8 * g4) = vv;
    }
  }
}

__global__ void proj_kernel(const float* __restrict__ OP, const float* __restrict__ LP,
                            const float* __restrict__ proj_w, const float* __restrict__ proj_b,
                            float* __restrict__ out, int SK) {
  __shared__ float pv[64][32];
  int bid = blockIdx.x;
  int b = bid >> 7;
  int n0 = (bid & 127) << 5;
  int t = threadIdx.x;
  int nl = t & 31;
  int g = t >> 5;
  int n = n0 + nl;
  {
    int h = g >> 1;
    float ls = 0.f;
    for (int s = 0; s < SK; ++s)
      ls += LP[(((size_t)s * 2 + b) * NH + h) * NN + n];
    float inv = 1.0f / ls;
#pragma unroll
    for (int cc = 0; cc < 8; ++cc) {
      int c = g * 8 + cc;
      int d = c & 15;
      float acc = 0.f;
      for (int s = 0; s < SK; ++s)
        acc += OP[((((size_t)s * 2 + b) * NH + h) * HD + d) * NN + n];
      pv[c][nl] = acc * inv;
    }
  }
  __syncthreads();
#pragma unroll
  for (int oo = 0; oo < 8; ++oo) {
    int o = g * 8 + oo;
    float acc = proj_b[o];
#pragma unroll
    for (int c = 0; c < 64; ++c) acc += proj_w[o * 64 + c] * pv[c][nl];
    out[((size_t)b * CC + o) * NN + n] = acc;
  }
}

extern "C" void kernel_launch(void* const* d_in, const int* in_sizes, int n_in,
                              void* d_out, int out_size, void* d_ws, size_t ws_size,
                              hipStream_t stream) {
  const float* x = (const float*)d_in[0];
  const float* tpm = (const float*)d_in[1];
  const float* qkv_w = (const float*)d_in[2];
  const float* qkv_b = (const float*)d_in[3];
  const float* proj_w = (const float*)d_in[4];
  const float* proj_b = (const float*)d_in[5];
  const float* temperature = (const float*)d_in[6];
  float* out = (float*)d_out;

  const size_t MB = 1u << 20;
  char* ws = (char*)d_ws;
  short* Q    = (short*)(ws);
  short* K    = (short*)(ws + 1 * MB);
  short* Kp   = (short*)(ws + 2 * MB);
  short* V    = (short*)(ws + 3 * MB);
  float* ts   = (float*)(ws + 4 * MB);
  short* ones = (short*)(ws + 4 * MB + 32768);
  size_t lp_off = 4 * MB + 49152;
  float* LP = (float*)(ws + lp_off);
  float* OP = (float*)(ws + lp_off + 4 * 128 * 1024);  // SK=4 layout

  size_t need = lp_off + 4 * 128 * 1024 + 4 * (2 * MB);
  bool coop_ok = (ws_size >= need);

  if (coop_ok) {
    void* args[] = {(void*)&x, (void*)&tpm, (void*)&qkv_w, (void*)&qkv_b, (void*)&temperature,
                    (void*)&proj_w, (void*)&proj_b, (void*)&out,
                    (void*)&Q, (void*)&K, (void*)&Kp, (void*)&V, (void*)&ts, (void*)&ones,
                    (void*)&OP, (void*)&LP};
    hipError_t err = hipLaunchCooperativeKernel((void*)fused_kernel, dim3(1024), dim3(256),
                                                args, 0, stream);
    if (err == hipSuccess) return;
  }

  // fallback: proven 3-kernel path
  int SK = 1;
  for (int cand = 4; cand >= 1; cand >>= 1) {
    size_t needk = lp_off + (size_t)cand * (128 * 1024) + (size_t)cand * (2 * MB);
    if (ws_size >= needk) { SK = cand; break; }
  }
  float* LPf = (float*)(ws + lp_off);
  float* OPf = (float*)(ws + lp_off + (size_t)SK * 128 * 1024);
  qkv_kernel<<<2 * 3 * 64, 256, 0, stream>>>(x, tpm, qkv_w, qkv_b, temperature, Q, K, Kp, V, ts, ones);
  attn_kernel<<<SK * 256, 256, 0, stream>>>(Q, K, Kp, V, ones, ts, OPf, LPf, NN / SK);
  proj_kernel<<<2 * 128, 256, 0, stream>>>(OPf, LPf, proj_w, proj_b, out, SK);
}

// Round 6
// 69.459 us; speedup vs baseline: 4.4709x; 4.4709x over previous
//
#include <hip/hip_runtime.h>
#include <hip/hip_bf16.h>
#include <math.h>

typedef __attribute__((ext_vector_type(8))) short bf16x8_t;
typedef __attribute__((ext_vector_type(4))) int i32x4_t;
typedef __attribute__((ext_vector_type(2))) int i32x2_t;
typedef __attribute__((ext_vector_type(4))) float f32x4_t;
typedef __attribute__((ext_vector_type(16))) float f32x16_t;

#define NH 4
#define HD 16
#define NN 4096
#define CC 64

__device__ __forceinline__ short f2bf(float f) {
  union { float f; unsigned u; } v; v.f = f;
  unsigned r = v.u + 0x7FFFu + ((v.u >> 16) & 1u);
  return (short)(r >> 16);
}

// ---------------- kernel 1: QKV + ts + Kp + ones ----------------
// grid: 2(b) x 3(which) x 64(n-tile of 64) = 384 blocks; 256 thr = 4 waves, wave = head.
// x tile staged in LDS (once per block, shared by 4 heads); w via wave-uniform s_load.
__global__ __launch_bounds__(256) void qkv_kernel(
    const float* __restrict__ x, const float* __restrict__ tpm,
    const float* __restrict__ qkv_w, const float* __restrict__ qkv_b,
    const float* __restrict__ temperature,
    short* __restrict__ Q, short* __restrict__ K, short* __restrict__ Kp,
    short* __restrict__ V, float* __restrict__ ts, short* __restrict__ ones) {
  __shared__ float xs[64][64];  // [c][n] 16 KB
  int bid = blockIdx.x;
  if (bid < 17) {
    int idx = bid * 256 + threadIdx.x;
    if (idx < 4352) ones[idx] = (short)0x3F80;
  }
  int nt = bid % 64;
  int which = (bid / 64) % 3;
  int b = bid / 192;
  int t = threadIdx.x;
  int nl = t & 63;
  int h = __builtin_amdgcn_readfirstlane(t >> 6);  // wave-uniform head -> w loads scalarize
  int n0 = nt * 64;
  int n = n0 + nl;

  {
    int c0 = t >> 6;
    const float* xb = x + ((size_t)b * 64) * NN + n0;
#pragma unroll
    for (int k = 0; k < 16; ++k) {
      int c = c0 + 4 * k;
      xs[c][nl] = xb[(size_t)c * NN + nl];
    }
  }
  __syncthreads();

  int obase = which * 64 + h * 16;
  float acc[16];
#pragma unroll
  for (int d = 0; d < 16; ++d) acc[d] = qkv_b[obase + d];

#pragma unroll 1
  for (int cb = 0; cb < 64; cb += 8) {
    float xr[8];
#pragma unroll
    for (int cc = 0; cc < 8; ++cc) xr[cc] = xs[cb + cc][nl];
#pragma unroll
    for (int d = 0; d < 16; ++d) {
#pragma unroll
      for (int cc = 0; cc < 8; ++cc)
        acc[d] += qkv_w[(obase + d) * 64 + cb + cc] * xr[cc];
    }
  }

  if (which == 2) {
    // V layout: [b][h][d][n]
#pragma unroll
    for (int d = 0; d < 16; ++d)
      V[(((size_t)b * NH + h) * HD + d) * NN + n] = f2bf(acc[d]);
    if (h == 0) {
      float tc = temperature[0];
      tc = fminf(fmaxf(tc, 0.1f), 2.0f);
      float tp = tpm[(size_t)b * NN + n];
      tp = fminf(fmaxf(tp, 0.01f), 1.0f);
      ts[(size_t)b * NN + n] = 0.125f * tc * tp * 1.44269504088896341f;
    }
  } else if (which == 0) {
    short pk[16];
#pragma unroll
    for (int d = 0; d < 16; ++d) pk[d] = f2bf(acc[d]);
    short* dst = Q + (((size_t)b * NH + h) * NN + n) * HD;
    *(bf16x8_t*)dst = *(bf16x8_t*)&pk[0];
    *(bf16x8_t*)(dst + 8) = *(bf16x8_t*)&pk[8];
  } else {
    float tc = temperature[0];
    tc = fminf(fmaxf(tc, 0.1f), 2.0f);
    float tp = tpm[(size_t)b * NN + n];
    tp = fminf(fmaxf(tp, 0.01f), 1.0f);
    float tsn = 0.125f * tc * tp * 1.44269504088896341f;
    short pk[16], pkp[16];
#pragma unroll
    for (int d = 0; d < 16; ++d) { pk[d] = f2bf(acc[d]); pkp[d] = f2bf(acc[d] * tsn); }
    short* dst = K + (((size_t)b * NH + h) * NN + n) * HD;
    *(bf16x8_t*)dst = *(bf16x8_t*)&pk[0];
    *(bf16x8_t*)(dst + 8) = *(bf16x8_t*)&pk[8];
    short* dstp = Kp + (((size_t)b * NH + h) * NN + n) * HD;
    *(bf16x8_t*)dstp = *(bf16x8_t*)&pkp[0];
    *(bf16x8_t*)(dstp + 8) = *(bf16x8_t*)&pkp[8];
  }
}

// ---------------- kernel 2: flash attention, swapped-QK^T, all-register P ----------------
// grid: SK * 8(bh) * 32(qtile); block 256 = 4 waves, each wave owns 32 q.
// OP partials in [seg][b][h][d][n] (n-fast) for coalesced proj reads; float4 epilogue.
__global__ __launch_bounds__(256, 4) void attn_kernel(
    const short* __restrict__ Q, const short* __restrict__ K, const short* __restrict__ Kp,
    const short* __restrict__ V, const short* __restrict__ ones, const float* __restrict__ ts,
    float* __restrict__ OP, float* __restrict__ LP, int jcount) {
  int bid = blockIdx.x;
  int tile = bid & 31;
  int bh = (bid >> 5) & 7;
  int seg = bid >> 8;
  int b = bh >> 2, h = bh & 3;

  int tid = threadIdx.x;
  int w = tid >> 6;
  int lane = tid & 63;
  int half = lane >> 5;
  int l31 = lane & 31;

  int qi0 = tile * 128 + w * 32;
  const short* Qb = Q + (((size_t)b * NH + h) * NN) * HD;
  const short* Kb = K + (((size_t)b * NH + h) * NN) * HD;
  const short* Kpb = Kp + (((size_t)b * NH + h) * NN) * HD;
  const short* Vb = V + (((size_t)b * NH + h) * HD) * NN;

  float tsi = ts[(size_t)b * NN + qi0 + l31];
  bf16x8_t qf = *(const bf16x8_t*)(Qb + (size_t)(qi0 + l31) * HD + 8 * half);

  int jbase = seg * jcount;
  const short* vrow = (l31 < 16) ? (Vb + (size_t)l31 * NN + jbase) : ones;

  f32x16_t acc = {0.f,0.f,0.f,0.f,0.f,0.f,0.f,0.f,0.f,0.f,0.f,0.f,0.f,0.f,0.f,0.f};
  const f32x16_t z16 = {0.f,0.f,0.f,0.f,0.f,0.f,0.f,0.f,0.f,0.f,0.f,0.f,0.f,0.f,0.f,0.f};

#pragma unroll 4
  for (int jj = 0; jj < jcount; jj += 32) {
    const short* kptr = Kb + (size_t)(jbase + jj + l31) * HD + 8 * half;
    const short* kpptr = Kpb + (size_t)(jbase + jj + l31) * HD + 8 * half;
    bf16x8_t ak = *(const bf16x8_t*)kptr;
    bf16x8_t akp = *(const bf16x8_t*)kpptr;
    f32x16_t s = __builtin_amdgcn_mfma_f32_32x32x16_bf16(ak, qf, z16, 0, 0, 0);
    f32x16_t sp = __builtin_amdgcn_mfma_f32_32x32x16_bf16(akp, qf, z16, 0, 0, 0);

    float p[16];
#pragma unroll
    for (int r = 0; r < 16; ++r)
      p[r] = __builtin_amdgcn_exp2f(s[r] * tsi + sp[r]);

    int wr[8];
#pragma unroll
    for (int m = 0; m < 8; ++m)
      asm("v_cvt_pk_bf16_f32 %0, %1, %2" : "=v"(wr[m]) : "v"(p[2 * m]), "v"(p[2 * m + 1]));

    i32x2_t s02 = __builtin_amdgcn_permlane32_swap(wr[0], wr[2], false, false);
    i32x2_t s13 = __builtin_amdgcn_permlane32_swap(wr[1], wr[3], false, false);
    i32x2_t s46 = __builtin_amdgcn_permlane32_swap(wr[4], wr[6], false, false);
    i32x2_t s57 = __builtin_amdgcn_permlane32_swap(wr[5], wr[7], false, false);
    union { i32x4_t i; bf16x8_t b; } pa0, pa1;
    pa0.i = (i32x4_t){s02[0], s13[0], s02[1], s13[1]};
    pa1.i = (i32x4_t){s46[0], s57[0], s46[1], s57[1]};

    bf16x8_t bv0 = *(const bf16x8_t*)(vrow + jj + 8 * half);
    bf16x8_t bv1 = *(const bf16x8_t*)(vrow + jj + 16 + 8 * half);
    acc = __builtin_amdgcn_mfma_f32_32x32x16_bf16(pa0.b, bv0, acc, 0, 0, 0);
    acc = __builtin_amdgcn_mfma_f32_32x32x16_bf16(pa1.b, bv1, acc, 0, 0, 0);
  }

  // rows r=4*g4+j -> n = qi0 + 8*g4 + 4*half + j  (contiguous float4 per g4)
  float* OPb = OP + ((((size_t)seg * 2 + b) * NH + h) * HD) * NN;
  float* LPb = LP + (((size_t)seg * 2 + b) * NH + h) * NN;
  if (l31 < 16) {
#pragma unroll
    for (int g4 = 0; g4 < 4; ++g4) {
      f32x4_t vv = {acc[4 * g4 + 0], acc[4 * g4 + 1], acc[4 * g4 + 2], acc[4 * g4 + 3]};
      *(f32x4_t*)(OPb + (size_t)l31 * NN + qi0 + 4 * half + 8 * g4) = vv;
    }
  } else if (l31 == 16) {
#pragma unroll
    for (int g4 = 0; g4 < 4; ++g4) {
      f32x4_t vv = {acc[4 * g4 + 0], acc[4 * g4 + 1], acc[4 * g4 + 2], acc[4 * g4 + 3]};
      *(f32x4_t*)(LPb + qi0 + 4 * half + 8 * g4) = vv;
    }
  }
}

// ---------------- kernel 3: merge partials + proj ----------------
// grid: B * 128 ; block 256 ; 32 n-columns per block. OP reads n-fast (coalesced).
__global__ void proj_kernel(const float* __restrict__ OP, const float* __restrict__ LP,
                            const float* __restrict__ proj_w, const float* __restrict__ proj_b,
                            float* __restrict__ out, int SK) {
  __shared__ float pv[64][32];
  int bid = blockIdx.x;
  int b = bid >> 7;
  int n0 = (bid & 127) << 5;
  int t = threadIdx.x;
  int nl = t & 31;
  int g = t >> 5;  // 0..7
  int n = n0 + nl;

  {
    int h = g >> 1;
    float ls = 0.f;
    for (int s = 0; s < SK; ++s)
      ls += LP[(((size_t)s * 2 + b) * NH + h) * NN + n];
    float inv = 1.0f / ls;
#pragma unroll
    for (int cc = 0; cc < 8; ++cc) {
      int c = g * 8 + cc;
      int d = c & 15;
      float acc = 0.f;
      for (int s = 0; s < SK; ++s)
        acc += OP[((((size_t)s * 2 + b) * NH + h) * HD + d) * NN + n];
      pv[c][nl] = acc * inv;
    }
  }
  __syncthreads();
#pragma unroll
  for (int oo = 0; oo < 8; ++oo) {
    int o = g * 8 + oo;
    float acc = proj_b[o];
#pragma unroll
    for (int c = 0; c < 64; ++c) acc += proj_w[o * 64 + c] * pv[c][nl];
    out[((size_t)b * CC + o) * NN + n] = acc;
  }
}

extern "C" void kernel_launch(void* const* d_in, const int* in_sizes, int n_in,
                              void* d_out, int out_size, void* d_ws, size_t ws_size,
                              hipStream_t stream) {
  const float* x = (const float*)d_in[0];
  const float* tpm = (const float*)d_in[1];
  const float* qkv_w = (const float*)d_in[2];
  const float* qkv_b = (const float*)d_in[3];
  const float* proj_w = (const float*)d_in[4];
  const float* proj_b = (const float*)d_in[5];
  const float* temperature = (const float*)d_in[6];
  float* out = (float*)d_out;

  const size_t MB = 1u << 20;
  char* ws = (char*)d_ws;
  short* Q    = (short*)(ws);
  short* K    = (short*)(ws + 1 * MB);
  short* Kp   = (short*)(ws + 2 * MB);
  short* V    = (short*)(ws + 3 * MB);
  float* ts   = (float*)(ws + 4 * MB);            // 32 KB
  short* ones = (short*)(ws + 4 * MB + 32768);    // 16 KB (4352 shorts used)
  size_t lp_off = 4 * MB + 49152;

  int SK = 1;
  for (int cand = 4; cand >= 1; cand >>= 1) {
    size_t need = lp_off + (size_t)cand * (128 * 1024) + (size_t)cand * (2 * MB);
    if (ws_size >= need) { SK = cand; break; }
  }
  float* LP = (float*)(ws + lp_off);
  float* OP = (float*)(ws + lp_off + (size_t)SK * 128 * 1024);

  qkv_kernel<<<2 * 3 * 64, 256, 0, stream>>>(x, tpm, qkv_w, qkv_b, temperature, Q, K, Kp, V, ts, ones);
  attn_kernel<<<SK * 256, 256, 0, stream>>>(Q, K, Kp, V, ones, ts, OP, LP, NN / SK);
  proj_kernel<<<2 * 128, 256, 0, stream>>>(OP, LP, proj_w, proj_b, out, SK);
}